// Round 3
// baseline (446.796 us; speedup 1.0000x reference)
//
#include <hip/hip_runtime.h>

#define NRAYS   65536      // B*T*R = 4*2*8192
#define NP      48         // samples per ray
#define NKP     64
#define OSTRIDE 69         // mask(1) + depth(1) + ch(3) + kp(64)
#define NPAIRS  8388608

// ---------------------------------------------------------------------------
// ws layout: [0..1] unsigned min/max bits of depths (global reduce),
//            floats from offset 16: wflat[NRAYS*NP] masked weights
// ---------------------------------------------------------------------------

__global__ void init_red(unsigned* __restrict__ red) {
  red[0] = 0x7F800000u;  // +inf bits (min identity for positive floats)
  red[1] = 0u;           // max identity for positive floats
}

__global__ __launch_bounds__(256) void composite_kernel(
    const float* __restrict__ shape,
    const float* __restrict__ depths,
    const float* __restrict__ channels,
    const int*   __restrict__ valid,
    float* __restrict__ out,
    float* __restrict__ wflat,
    unsigned* __restrict__ red)
{
  const int ray = blockIdx.x * blockDim.x + threadIdx.x;  // grid covers NRAYS exactly

  const float4* s4 = reinterpret_cast<const float4*>(shape   + (size_t)ray * NP);
  const float4* d4 = reinterpret_cast<const float4*>(depths  + (size_t)ray * NP);
  const int4*   v4 = reinterpret_cast<const int4*>  (valid   + (size_t)ray * NP);
  const float4* c4 = reinterpret_cast<const float4*>(channels + (size_t)ray * NP * 3);
  float4*       w4 = reinterpret_cast<float4*>      (wflat   + (size_t)ray * NP);

  float T = 1.0f;                 // transmittance (cumprod of shifted 1-alpha)
  float wt = 0.0f, wd = 0.0f;     // weight total, weighted depth
  float c0 = 0.0f, c1 = 0.0f, c2 = 0.0f;
  float dmin = __int_as_float(0x7F800000);  // +inf
  float dmax = 0.0f;                         // depths > 0.5 always

#pragma unroll
  for (int c = 0; c < NP / 4; ++c) {
    float4 s = s4[c];
    float4 d = d4[c];
    int4   v = v4[c];
    float4 ca = c4[c * 3 + 0];
    float4 cb = c4[c * 3 + 1];
    float4 cc = c4[c * 3 + 2];
    float sv[4]  = {s.x, s.y, s.z, s.w};
    float dv[4]  = {d.x, d.y, d.z, d.w};
    int   vv[4]  = {v.x, v.y, v.z, v.w};
    float cf[12] = {ca.x, ca.y, ca.z, ca.w, cb.x, cb.y, cb.z, cb.w,
                    cc.x, cc.y, cc.z, cc.w};
    float wv[4];
#pragma unroll
    for (int j = 0; j < 4; ++j) {
      // precise expf: weights feed a 48-step cumprod + 8.4M-pair scatter;
      // kernel is memory-bound so the extra VALU cost is hidden.
      float a = 1.0f / (1.0f + expf(-sv[j]));   // sigmoid
      float w = a * T;                          // alpha * transmittance
      T = T * ((1.0f - a) + 1e-10f);            // match reference op order
      wt += w;
      wd += w * dv[j];
      float wm = vv[j] ? w : 0.0f;              // masked weight
      wv[j] = wm;
      c0 += wm * cf[3 * j + 0];
      c1 += wm * cf[3 * j + 1];
      c2 += wm * cf[3 * j + 2];
      dmin = fminf(dmin, dv[j]);
      dmax = fmaxf(dmax, dv[j]);
    }
    w4[c] = make_float4(wv[0], wv[1], wv[2], wv[3]);
  }

  const size_t ob = (size_t)ray * OSTRIDE;
  out[ob + 0] = fminf(fmaxf(wt, 0.0f), 1.0f);   // mask
  out[ob + 1] = wd / wt;                        // depth, clipped in finalize
  out[ob + 2] = fminf(fmaxf(c0, 0.0f), 1.0f);
  out[ob + 3] = fminf(fmaxf(c1, 0.0f), 1.0f);
  out[ob + 4] = fminf(fmaxf(c2, 0.0f), 1.0f);
  // kp region out[ob+5 .. ob+68] was zeroed by the memset; scatter adds later.

  // wave-level min/max reduce, one atomic per wave (positive-float bit trick)
#pragma unroll
  for (int o = 32; o >= 1; o >>= 1) {
    dmin = fminf(dmin, __shfl_xor(dmin, o, 64));
    dmax = fmaxf(dmax, __shfl_xor(dmax, o, 64));
  }
  if ((threadIdx.x & 63) == 0) {
    atomicMin(&red[0], __float_as_uint(dmin));
    atomicMax(&red[1], __float_as_uint(dmax));
  }
}

__global__ __launch_bounds__(256) void scatter_kernel(
    const float* __restrict__ kp_w,
    const int*   __restrict__ sidx,
    const int*   __restrict__ kidx,
    const float* __restrict__ wflat,
    float* __restrict__ out)
{
  const int t = blockIdx.x * blockDim.x + threadIdx.x;  // 4 pairs per thread
  int4   si = reinterpret_cast<const int4*>(sidx)[t];
  int4   ki = reinterpret_cast<const int4*>(kidx)[t];
  float4 w  = reinterpret_cast<const float4*>(kp_w)[t];
  const int   ss[4] = {si.x, si.y, si.z, si.w};
  const int   kk[4] = {ki.x, ki.y, ki.z, ki.w};
  const float ww[4] = {w.x, w.y, w.z, w.w};
#pragma unroll
  for (int j = 0; j < 4; ++j) {
    float val = wflat[ss[j]] * ww[j];
    if (val != 0.0f) {                       // ~50% masked out: skip the atomic
      unsigned ray = (unsigned)ss[j] / (unsigned)NP;
      atomicAdd(&out[(size_t)ray * OSTRIDE + 5u + (unsigned)kk[j]], val);
    }
  }
}

__global__ __launch_bounds__(256) void finalize_kernel(
    float* __restrict__ out, const unsigned* __restrict__ red)
{
  const int t   = blockIdx.x * blockDim.x + threadIdx.x;  // NRAYS*NKP threads
  const int ray = t >> 6;
  const int k   = t & 63;
  const size_t ob = (size_t)ray * OSTRIDE;
  float v = out[ob + 5 + k];
  out[ob + 5 + k] = fminf(fmaxf(v, 0.0f), 1.0f);
  if (k == 0) {
    const float gmin = __uint_as_float(red[0]);
    const float gmax = __uint_as_float(red[1]);
    float d = out[ob + 1];
    if (d != d) d = __int_as_float(0x7F800000);  // NaN -> inf
    d = fminf(fmaxf(d, gmin), gmax);             // clip to global depth range
    out[ob + 1] = d;
  }
}

extern "C" void kernel_launch(void* const* d_in, const int* in_sizes, int n_in,
                              void* d_out, int out_size, void* d_ws, size_t ws_size,
                              hipStream_t stream) {
  const float* shape    = (const float*)d_in[0];
  const float* depths   = (const float*)d_in[1];
  const float* channels = (const float*)d_in[2];
  const float* kp_w     = (const float*)d_in[3];
  const int*   kp_sidx  = (const int*)  d_in[4];
  const int*   kp_kidx  = (const int*)  d_in[5];
  const int*   valid    = (const int*)  d_in[6];
  // d_in[7] = num_kp (scalar, == 64, hardcoded)

  float*    out   = (float*)d_out;
  unsigned* red   = (unsigned*)d_ws;
  float*    wflat = (float*)d_ws + 16;  // 64-byte offset

  hipMemsetAsync(d_out, 0, (size_t)out_size * sizeof(float), stream);
  init_red<<<1, 1, 0, stream>>>(red);
  composite_kernel<<<NRAYS / 256, 256, 0, stream>>>(
      shape, depths, channels, valid, out, wflat, red);
  scatter_kernel<<<NPAIRS / 4 / 256, 256, 0, stream>>>(
      kp_w, kp_sidx, kp_kidx, wflat, out);
  finalize_kernel<<<NRAYS * NKP / 256, 256, 0, stream>>>(out, red);
}

// Round 4
// 387.297 us; speedup vs baseline: 1.1536x; 1.1536x over previous
//
#include <hip/hip_runtime.h>
#include <hip/hip_fp16.h>

#define NRAYS   65536      // B*T*R = 4*2*8192
#define NP      48         // samples per ray
#define NKP     64
#define OSTRIDE 69         // mask(1) + depth(1) + ch(3) + kp(64)
#define NPAIRS  8388608

// ws layout: [0..1] unsigned min/max bits of depths (global reduce),
//            from byte offset 64: wflat[NRAYS*NP] masked weights as fp16

__global__ void init_red(unsigned* __restrict__ red) {
  red[0] = 0x7F800000u;  // +inf bits (min identity for positive floats)
  red[1] = 0u;           // max identity for positive floats
}

// 4 lanes per ray; lane `seg` owns samples [12*seg, 12*seg+12).
// Transmittance is a product recurrence: w_i = a_i * prod_{k<i} f_k,
// f_k = (1-a_k)+1e-10. Each lane computes its local prefix assuming T=1,
// then scales by the true prefix Tpre = prod of earlier segments' products
// (3 shfls). All composites are linear in Tpre, so partial sums scale.
__global__ __launch_bounds__(256) void composite_kernel(
    const float* __restrict__ shape,
    const float* __restrict__ depths,
    const float* __restrict__ channels,
    const int*   __restrict__ valid,
    float* __restrict__ out,
    unsigned short* __restrict__ wflat,
    unsigned* __restrict__ red)
{
  const int gt   = blockIdx.x * blockDim.x + threadIdx.x;
  const int ray  = gt >> 2;          // 64 rays per 256-thread block
  const int seg  = gt & 3;
  const int lane = threadIdx.x & 63;

  // per-lane bases (48B-contiguous lane stride -> L1-friendly)
  const float4* s4 = reinterpret_cast<const float4*>(shape  + (size_t)ray * NP + seg * 12);
  const float4* d4 = reinterpret_cast<const float4*>(depths + (size_t)ray * NP + seg * 12);
  const int4*   v4 = reinterpret_cast<const int4*>  (valid  + (size_t)ray * NP + seg * 12);
  const float4* c4 = reinterpret_cast<const float4*>(channels + (size_t)ray * NP * 3 + seg * 36);

  float Tl = 1.0f;                 // local transmittance (seg-start = 1)
  float wt = 0.0f, wd = 0.0f;      // local weight total / weighted depth
  float c0 = 0.0f, c1 = 0.0f, c2 = 0.0f;
  float wm[12];                    // local masked weights (unscaled)
  float dmin = __int_as_float(0x7F800000);
  float dmax = 0.0f;

#pragma unroll
  for (int c = 0; c < 3; ++c) {    // 3 chunks of 4 samples
    float4 s = s4[c];
    float4 d = d4[c];
    int4   v = v4[c];
    float4 ca = c4[c * 3 + 0];
    float4 cb = c4[c * 3 + 1];
    float4 cc = c4[c * 3 + 2];
    float sv[4]  = {s.x, s.y, s.z, s.w};
    float dv[4]  = {d.x, d.y, d.z, d.w};
    int   vv[4]  = {v.x, v.y, v.z, v.w};
    float cf[12] = {ca.x, ca.y, ca.z, ca.w, cb.x, cb.y, cb.z, cb.w,
                    cc.x, cc.y, cc.z, cc.w};
#pragma unroll
    for (int j = 0; j < 4; ++j) {
      float a = 1.0f / (1.0f + expf(-sv[j]));   // sigmoid (precise expf)
      float w = a * Tl;
      Tl = Tl * ((1.0f - a) + 1e-10f);          // reference op order
      wt += w;
      wd += w * dv[j];
      float m = vv[j] ? w : 0.0f;
      wm[c * 4 + j] = m;
      c0 += m * cf[3 * j + 0];
      c1 += m * cf[3 * j + 1];
      c2 += m * cf[3 * j + 2];
      dmin = fminf(dmin, dv[j]);
      dmax = fmaxf(dmax, dv[j]);
    }
  }

  // prefix product over the 4-lane group
  const int base = lane & ~3;
  const float P0 = __shfl(Tl, base + 0, 64);
  const float P1 = __shfl(Tl, base + 1, 64);
  const float P2 = __shfl(Tl, base + 2, 64);
  float Tpre = 1.0f;
  if (seg > 0) Tpre *= P0;
  if (seg > 1) Tpre *= P1;
  if (seg > 2) Tpre *= P2;

  // scale local partials to true values, then 4-lane butterfly sum
  wt *= Tpre; wd *= Tpre; c0 *= Tpre; c1 *= Tpre; c2 *= Tpre;
  wt += __shfl_xor(wt, 1, 64); wt += __shfl_xor(wt, 2, 64);
  wd += __shfl_xor(wd, 1, 64); wd += __shfl_xor(wd, 2, 64);
  c0 += __shfl_xor(c0, 1, 64); c0 += __shfl_xor(c0, 2, 64);
  c1 += __shfl_xor(c1, 1, 64); c1 += __shfl_xor(c1, 2, 64);
  c2 += __shfl_xor(c2, 1, 64); c2 += __shfl_xor(c2, 2, 64);

  // store masked weights (scaled) as fp16 — halves the scatter gather table
  ushort4* w4o = reinterpret_cast<ushort4*>(wflat + (size_t)ray * NP + seg * 12);
#pragma unroll
  for (int c = 0; c < 3; ++c) {
    ushort4 h;
    h.x = __half_as_ushort(__float2half(Tpre * wm[c * 4 + 0]));
    h.y = __half_as_ushort(__float2half(Tpre * wm[c * 4 + 1]));
    h.z = __half_as_ushort(__float2half(Tpre * wm[c * 4 + 2]));
    h.w = __half_as_ushort(__float2half(Tpre * wm[c * 4 + 3]));
    w4o[c] = h;
  }

  if (seg == 0) {
    const size_t ob = (size_t)ray * OSTRIDE;
    out[ob + 0] = fminf(fmaxf(wt, 0.0f), 1.0f);   // mask
    out[ob + 1] = wd / wt;                        // depth (clipped in finalize)
    out[ob + 2] = fminf(fmaxf(c0, 0.0f), 1.0f);
    out[ob + 3] = fminf(fmaxf(c1, 0.0f), 1.0f);
    out[ob + 4] = fminf(fmaxf(c2, 0.0f), 1.0f);
  }

  // global depth min/max: wave butterfly + one atomic per wave
#pragma unroll
  for (int o = 32; o >= 1; o >>= 1) {
    dmin = fminf(dmin, __shfl_xor(dmin, o, 64));
    dmax = fmaxf(dmax, __shfl_xor(dmax, o, 64));
  }
  if (lane == 0) {
    atomicMin(&red[0], __float_as_uint(dmin));
    atomicMax(&red[1], __float_as_uint(dmax));
  }
}

__global__ __launch_bounds__(256) void scatter_kernel(
    const float* __restrict__ kp_w,
    const int*   __restrict__ sidx,
    const int*   __restrict__ kidx,
    const unsigned short* __restrict__ wflat,
    float* __restrict__ out)
{
  const int t = blockIdx.x * blockDim.x + threadIdx.x;  // 8 pairs per thread
  const int4*   s4 = reinterpret_cast<const int4*>(sidx);
  const int4*   k4 = reinterpret_cast<const int4*>(kidx);
  const float4* w4 = reinterpret_cast<const float4*>(kp_w);

  int4 si0 = s4[2 * t], si1 = s4[2 * t + 1];
  const int ss[8] = {si0.x, si0.y, si0.z, si0.w, si1.x, si1.y, si1.z, si1.w};

  // issue all 8 gathers before anything depends on them
  unsigned short g[8];
#pragma unroll
  for (int j = 0; j < 8; ++j) g[j] = wflat[ss[j]];

  int4   ki0 = k4[2 * t], ki1 = k4[2 * t + 1];
  float4 w0  = w4[2 * t], w1  = w4[2 * t + 1];
  const int   kk[8] = {ki0.x, ki0.y, ki0.z, ki0.w, ki1.x, ki1.y, ki1.z, ki1.w};
  const float ww[8] = {w0.x, w0.y, w0.z, w0.w, w1.x, w1.y, w1.z, w1.w};

#pragma unroll
  for (int j = 0; j < 8; ++j) {
    float val = __half2float(__ushort_as_half(g[j])) * ww[j];
    if (val != 0.0f) {                       // ~50% masked: skip the atomic
      unsigned ray = (unsigned)ss[j] / (unsigned)NP;
      atomicAdd(&out[(size_t)ray * OSTRIDE + 5u + (unsigned)kk[j]], val);
    }
  }
}

__global__ __launch_bounds__(256) void finalize_kernel(
    float* __restrict__ out, const unsigned* __restrict__ red)
{
  const int t   = blockIdx.x * blockDim.x + threadIdx.x;  // NRAYS*NKP threads
  const int ray = t >> 6;
  const int k   = t & 63;
  const size_t ob = (size_t)ray * OSTRIDE;
  float v = out[ob + 5 + k];
  out[ob + 5 + k] = fminf(fmaxf(v, 0.0f), 1.0f);
  if (k == 0) {
    const float gmin = __uint_as_float(red[0]);
    const float gmax = __uint_as_float(red[1]);
    float d = out[ob + 1];
    if (d != d) d = __int_as_float(0x7F800000);  // NaN -> inf
    d = fminf(fmaxf(d, gmin), gmax);             // clip to global depth range
    out[ob + 1] = d;
  }
}

extern "C" void kernel_launch(void* const* d_in, const int* in_sizes, int n_in,
                              void* d_out, int out_size, void* d_ws, size_t ws_size,
                              hipStream_t stream) {
  const float* shape    = (const float*)d_in[0];
  const float* depths   = (const float*)d_in[1];
  const float* channels = (const float*)d_in[2];
  const float* kp_w     = (const float*)d_in[3];
  const int*   kp_sidx  = (const int*)  d_in[4];
  const int*   kp_kidx  = (const int*)  d_in[5];
  const int*   valid    = (const int*)  d_in[6];
  // d_in[7] = num_kp (scalar, == 64, hardcoded)

  float*          out   = (float*)d_out;
  unsigned*       red   = (unsigned*)d_ws;
  unsigned short* wflat = (unsigned short*)((char*)d_ws + 64);

  hipMemsetAsync(d_out, 0, (size_t)out_size * sizeof(float), stream);
  init_red<<<1, 1, 0, stream>>>(red);
  composite_kernel<<<NRAYS * 4 / 256, 256, 0, stream>>>(
      shape, depths, channels, valid, out, wflat, red);
  scatter_kernel<<<NPAIRS / 8 / 256, 256, 0, stream>>>(
      kp_w, kp_sidx, kp_kidx, wflat, out);
  finalize_kernel<<<NRAYS * NKP / 256, 256, 0, stream>>>(out, red);
}